// Round 6
// baseline (253.752 us; speedup 1.0000x reference)
//
#include <hip/hip_runtime.h>
#include <hip/hip_cooperative_groups.h>

namespace cg = cooperative_groups;

#define NTOK 65536
#define DIN 128
#define DH 256
#define DOUT 128
#define NEXP 8
#define NPAIR 28
#define CAP 12288
#define TAUF 5.0f
#define CSTRIDE 32   // cnt padded: one counter per 128 B

typedef __attribute__((ext_vector_type(8))) short short8;
typedef __attribute__((ext_vector_type(4))) float f32x4;

// ---- workspace layout (bytes) ----
#define OFF_CNT  0                              // 28 ints @ stride 32 ints
#define OFF_WG   4096                           // 1024 f32
#define OFF_BG   8192                           // 8 f32
#define OFF_W1F  8448                           // 8*128*256 bf16 = 524288
#define OFF_W2F  (OFF_W1F + NEXP*DIN*DH*2)      // 524288
#define OFF_L    (OFF_W2F + NEXP*DH*DOUT*2)     // 28*12288*16 = 5505024
// total ~6.6 MB

struct PrepS { float sl[32 * 257]; };
struct GateS {
  float xl[64 * 132];
  float pr[256 * 9];
  float wgl[1024];
  float bgl[8];
  int lc[NPAIR], lb[NPAIR];
};
struct ExpS {
  int cs[NPAIR];
  int toks[64];
  float wAs[64], wBs[64];
  unsigned short xs[64 * 136];
  unsigned short hs[64 * 264];
};
#define SMEM_BYTES 52096   // >= max(sizeof(PrepS), sizeof(GateS), sizeof(ExpS))

__device__ __forceinline__ unsigned short f2bf(float f) {
  union { float f; unsigned u; } v; v.f = f;
  unsigned u = v.u;
  return (unsigned short)((u + 0x7FFFu + ((u >> 16) & 1u)) >> 16);
}

__global__ void __launch_bounds__(256, 2) k_fused(
    const float* __restrict__ x,
    const float* __restrict__ Wp, const float* __restrict__ bp, const float* __restrict__ Ee,
    const float* __restrict__ W1, const float* __restrict__ b1,
    const float* __restrict__ W2, const float* __restrict__ b2,
    unsigned short* __restrict__ W1F, unsigned short* __restrict__ W2F,
    float* __restrict__ Wg, float* __restrict__ bg,
    int* __restrict__ cnt, uint4* __restrict__ lst,
    float* __restrict__ pout, float* __restrict__ aux, float* __restrict__ out) {
  __shared__ __align__(16) char smem[SMEM_BYTES];
  int t = threadIdx.x, b = blockIdx.x, G = gridDim.x;

  // ================= phase 1: prep (weight conv + gate fuse + zeroing) =================
  {
    PrepS* sp = (PrepS*)smem;
    for (int job = b; job < 97; job += G) {
      __syncthreads();
      if (job == 96) {
        for (int i = 0; i < 4; i++) {
          int o = t + i * 256;
          int k = o >> 3, e = o & 7;
          float s = 0.f;
          for (int l = 0; l < 64; l++) s += Wp[k * 64 + l] * Ee[l * 8 + e];
          Wg[o] = s;
        }
        if (t < 8) {
          float s = 0.f;
          for (int l = 0; l < 64; l++) s += bp[l] * Ee[l * 8 + t];
          bg[t] = s;
        }
        if (t < NPAIR) cnt[t * CSTRIDE] = 0;
        if (t == 255) aux[0] = 0.f;
      } else {
        const float* src; unsigned short* dst;
        int stride, iters, cshift;
        if (job < 32) {
          int e = job >> 2, kk = job & 3;
          src = W1 + e * (DIN * DH) + kk * 32 * DH;
          dst = W1F + e * (DIN * DH) + kk * (32 * DH);
          stride = 257; iters = 32; cshift = 8;           // 32 x 256 slab
        } else {
          int bb = job - 32;
          int e = bb >> 3, kk = bb & 7;
          src = W2 + e * (DH * DOUT) + kk * 32 * DOUT;
          dst = W2F + e * (DH * DOUT) + kk * (32 * DOUT);
          stride = 129; iters = 16; cshift = 7;           // 32 x 128 slab
        }
        int ncols_m1 = (1 << cshift) - 1;
        for (int i = 0; i < iters; i++) {
          int idx = t + i * 256;
          int r = idx >> cshift, c = idx & ncols_m1;
          sp->sl[r * stride + c] = src[idx];
        }
        __syncthreads();
        for (int i = 0; i < iters; i++) {
          int o = t + i * 256;                            // o = n*32 + c : B-frag linear
          int n = o >> 5, cc = o & 31;
          dst[o] = f2bf(sp->sl[cc * stride + n]);
        }
      }
    }
  }
  cg::this_grid().sync();

  // ================= phase 2: gate (grid-stride over 1024 chunks of 64 tokens) =================
  {
    GateS* sg = (GateS*)smem;
    for (int i = 0; i < 4; i++) sg->wgl[t + i * 256] = Wg[t + i * 256];
    if (t < 8) sg->bgl[t] = bg[t];
    for (int ch = b; ch < NTOK / 64; ch += G) {
      int tok0 = ch * 64;
      if (t < NPAIR) sg->lc[t] = 0;
      __syncthreads();
      const float4* x4 = (const float4*)(x + (size_t)tok0 * DIN);
      for (int i = 0; i < 8; i++) {
        int idx = t + i * 256;
        int r = idx >> 5, c4 = idx & 31;
        *(float4*)&sg->xl[r * 132 + c4 * 4] = x4[r * 32 + c4];
      }
      __syncthreads();
      {
        int tok = t & 63, seg = t >> 6;
        float a0=0,a1=0,a2=0,a3=0,a4=0,a5=0,a6=0,a7=0;
        int k0 = seg * 32;
        for (int k = k0; k < k0 + 32; k++) {
          float xv = sg->xl[tok * 132 + k];
          float4 wa = *(const float4*)&sg->wgl[k * 8];
          float4 wb = *(const float4*)&sg->wgl[k * 8 + 4];
          a0 += xv * wa.x; a1 += xv * wa.y; a2 += xv * wa.z; a3 += xv * wa.w;
          a4 += xv * wb.x; a5 += xv * wb.y; a6 += xv * wb.z; a7 += xv * wb.w;
        }
        float* p = &sg->pr[t * 9];
        p[0]=a0; p[1]=a1; p[2]=a2; p[3]=a3; p[4]=a4; p[5]=a5; p[6]=a6; p[7]=a7;
      }
      __syncthreads();
      int pid = 0; unsigned pos = 0; unsigned wAb = 0, wBb = 0;
      if (t < 64) {
        float p[8];
        #pragma unroll
        for (int e = 0; e < 8; e++) {
          float lg = sg->pr[t*9+e] + sg->pr[(64+t)*9+e] + sg->pr[(128+t)*9+e]
                   + sg->pr[(192+t)*9+e] + sg->bgl[e];
          p[e] = 1.f / (1.f + expf(-lg / TAUF));
        }
        float* prow = pout + (size_t)(tok0 + t) * 8;
        #pragma unroll
        for (int e = 0; e < 8; e++) prow[e] = p[e];
        int i0 = 0; float v0 = -1.f;
        #pragma unroll
        for (int e = 0; e < 8; e++) if (p[e] > v0) { v0 = p[e]; i0 = e; }
        int i1 = -1; float v1 = -1.f;
        #pragma unroll
        for (int e = 0; e < 8; e++) if (e != i0 && p[e] > v1) { v1 = p[e]; i1 = e; }
        float s = v0 + v1 + 1e-10f;
        float w0 = v0 / s, w1 = v1 / s;
        int eA, eB; float wA, wB;
        if (i0 < i1) { eA = i0; eB = i1; wA = w0; wB = w1; }
        else         { eA = i1; eB = i0; wA = w1; wB = w0; }
        pid = 7 * eA - (eA * (eA - 1)) / 2 + (eB - eA - 1);   // 28 unordered pairs
        union { float f; unsigned u; } ua, ub; ua.f = wA; ub.f = wB;
        wAb = ua.u; wBb = ub.u;
        pos = (unsigned)atomicAdd(&sg->lc[pid], 1);   // LDS atomic
      }
      __syncthreads();
      if (t < NPAIR) sg->lb[t] = atomicAdd(&cnt[t * CSTRIDE], sg->lc[t]);
      __syncthreads();
      if (t < 64) {
        int gi = sg->lb[pid] + (int)pos;
        if (gi < CAP) lst[pid * CAP + gi] = make_uint4((unsigned)(tok0 + t), wAb, wBb, 0u);
      }
    }
  }
  cg::this_grid().sync();

  // ================= phase 3: expert (grid-stride over tiles) =================
  {
    ExpS* se = (ExpS*)smem;
    if (t < NPAIR) se->cs[t] = cnt[t * CSTRIDE];
    int itmax = (1056 + G - 1) / G;
    int lane = t & 63, w = t >> 6;
    int q = lane >> 4, n16 = lane & 15;
    const f32x4 vz = {0.f, 0.f, 0.f, 0.f};
    int mb = (w & 1) * 2;
    int cb = (w >> 1) * 64;
    for (int iter = 0; iter < itmax; iter++) {
      int gid = b + iter * G;
      __syncthreads();   // protects cs (iter 0) and LDS reuse across tiles
      int bsel = -1, tIn = 0, cum = 0;
      #pragma unroll
      for (int bb = 0; bb < NPAIR; bb++) {
        int c = se->cs[bb]; c = (c > CAP) ? CAP : c;
        int tb = (c + 63) >> 6;
        if (bsel < 0 && gid < cum + tb) { bsel = bb; tIn = gid - cum; }
        cum += tb;
      }
      if (bsel < 0) continue;
      int eA = 0, eB = 1;
      { int r = bsel;
        #pragma unroll
        for (int a = 0; a < 7; a++) { int span = 7 - a; if (r < span) { eA = a; eB = a + 1 + r; break; } r -= span; } }
      int cntb = se->cs[bsel]; cntb = (cntb > CAP) ? CAP : cntb;
      int start = tIn * 64;
      int cvalid = min(64, cntb - start);
      if (t < 64) {
        if (t < cvalid) {
          uint4 en = lst[bsel * CAP + start + t];
          se->toks[t] = (int)en.x;
          union { unsigned u; float f; } ua, ub; ua.u = en.y; ub.u = en.z;
          se->wAs[t] = ua.f; se->wBs[t] = ub.f;
        } else { se->toks[t] = 0; se->wAs[t] = 0.f; se->wBs[t] = 0.f; }
      }
      __syncthreads();
      for (int i = 0; i < 8; i++) {          // gather x rows -> bf16 LDS
        int idx = i * 256 + t;
        int r = idx >> 5, c4 = idx & 31;
        float4 f = *(const float4*)(x + (size_t)se->toks[r] * DIN + c4 * 4);
        unsigned u0 = (unsigned)f2bf(f.x) | ((unsigned)f2bf(f.y) << 16);
        unsigned u1 = (unsigned)f2bf(f.z) | ((unsigned)f2bf(f.w) << 16);
        *(uint2*)(se->xs + r * 136 + c4 * 4) = make_uint2(u0, u1);
      }
      __syncthreads();
      f32x4 accO[2][4];
      for (int pass = 0; pass < 2; pass++) {
        int e = pass ? eB : eA;
        if (pass) __syncthreads();   // all waves done reading hs from pass 0
        // ---- GEMM1: H = relu(X @ W1[e] + b1[e]); wave w -> hidden cols [w*64, +64) ----
        {
          const unsigned short* Bp = W1F + e * (DIN * DH) + (w * 64 + n16) * 32 + q * 8;
          float b1v[4];
          #pragma unroll
          for (int nt = 0; nt < 4; nt++) b1v[nt] = b1[e * DH + w * 64 + nt * 16 + n16];
          f32x4 acc[4][4];
          #pragma unroll
          for (int mt = 0; mt < 4; mt++)
            #pragma unroll
            for (int nt = 0; nt < 4; nt++) acc[mt][nt] = vz;
          short8 bcur[4], bnxt[4];
          #pragma unroll
          for (int nt = 0; nt < 4; nt++) bcur[nt] = *(const short8*)(Bp + nt * 512);
          #pragma unroll
          for (int kk = 0; kk < 4; kk++) {
            if (kk < 3) {
              #pragma unroll
              for (int nt = 0; nt < 4; nt++) bnxt[nt] = *(const short8*)(Bp + (kk + 1) * 8192 + nt * 512);
            }
            short8 a[4];
            #pragma unroll
            for (int mt = 0; mt < 4; mt++)
              a[mt] = *(const short8*)(se->xs + (mt * 16 + n16) * 136 + kk * 32 + q * 8);
            #pragma unroll
            for (int nt = 0; nt < 4; nt++)
              #pragma unroll
              for (int mt = 0; mt < 4; mt++)
                acc[mt][nt] = __builtin_amdgcn_mfma_f32_16x16x32_bf16(a[mt], bcur[nt], acc[mt][nt], 0, 0, 0);
            #pragma unroll
            for (int nt = 0; nt < 4; nt++) bcur[nt] = bnxt[nt];
          }
          #pragma unroll
          for (int mt = 0; mt < 4; mt++)
            #pragma unroll
            for (int nt = 0; nt < 4; nt++)
              #pragma unroll
              for (int r = 0; r < 4; r++) {
                float v = fmaxf(acc[mt][nt][r] + b1v[nt], 0.f);
                se->hs[(mt * 16 + q * 4 + r) * 264 + w * 64 + nt * 16 + n16] = f2bf(v);
              }
        }
        __syncthreads();
        // ---- GEMM2: acc2 = H @ W2[e]; wave -> rows [(w&1)*32,+32), cols [(w>>1)*64,+64) ----
        {
          const unsigned short* Bp = W2F + e * (DH * DOUT) + (cb + n16) * 32 + q * 8;
          float b2v[4];
          #pragma unroll
          for (int nt = 0; nt < 4; nt++) b2v[nt] = b2[e * DOUT + cb + nt * 16 + n16];
          f32x4 acc2[2][4];
          #pragma unroll
          for (int m = 0; m < 2; m++)
            #pragma unroll
            for (int nt = 0; nt < 4; nt++) acc2[m][nt] = vz;
          short8 bcur[8], bnxt[8];
          #pragma unroll
          for (int i = 0; i < 8; i++)
            bcur[i] = *(const short8*)(Bp + (i >> 2) * 4096 + (i & 3) * 512);
          #pragma unroll
          for (int kc = 0; kc < 4; kc++) {
            if (kc < 3) {
              #pragma unroll
              for (int i = 0; i < 8; i++)
                bnxt[i] = *(const short8*)(Bp + (kc * 2 + 2 + (i >> 2)) * 4096 + (i & 3) * 512);
            }
            #pragma unroll
            for (int kk2 = 0; kk2 < 2; kk2++) {
              int kk = kc * 2 + kk2;
              short8 a[2];
              #pragma unroll
              for (int m = 0; m < 2; m++)
                a[m] = *(const short8*)(se->hs + ((mb + m) * 16 + n16) * 264 + kk * 32 + q * 8);
              #pragma unroll
              for (int nt = 0; nt < 4; nt++)
                #pragma unroll
                for (int m = 0; m < 2; m++)
                  acc2[m][nt] = __builtin_amdgcn_mfma_f32_16x16x32_bf16(a[m], bcur[kk2 * 4 + nt], acc2[m][nt], 0, 0, 0);
            }
            #pragma unroll
            for (int i = 0; i < 8; i++) bcur[i] = bnxt[i];
          }
          const float* wsel = pass ? se->wBs : se->wAs;
          #pragma unroll
          for (int m = 0; m < 2; m++)
            #pragma unroll
            for (int r = 0; r < 4; r++) {
              float wv = wsel[(mb + m) * 16 + q * 4 + r];
              #pragma unroll
              for (int nt = 0; nt < 4; nt++) {
                float v = (acc2[m][nt][r] + b2v[nt]) * wv;
                if (pass) accO[m][nt][r] += v;
                else      accO[m][nt][r] = v;
              }
            }
        }
      }
      // single store per output element
      #pragma unroll
      for (int m = 0; m < 2; m++)
        #pragma unroll
        for (int r = 0; r < 4; r++) {
          int row = (mb + m) * 16 + q * 4 + r;
          if (row < cvalid) {
            float* orow = out + (size_t)se->toks[row] * DOUT + cb + n16;
            #pragma unroll
            for (int nt = 0; nt < 4; nt++) orow[nt * 16] = accO[m][nt][r];
          }
        }
    }
  }
}

extern "C" void kernel_launch(void* const* d_in, const int* in_sizes, int n_in,
                              void* d_out, int out_size, void* d_ws, size_t ws_size,
                              hipStream_t stream) {
  const float* x  = (const float*)d_in[0];
  const float* Wp = (const float*)d_in[1];
  const float* bp = (const float*)d_in[2];
  const float* Ee = (const float*)d_in[3];
  const float* W1 = (const float*)d_in[4];
  const float* b1 = (const float*)d_in[5];
  const float* W2 = (const float*)d_in[6];
  const float* b2 = (const float*)d_in[7];
  float* out = (float*)d_out;
  char* ws = (char*)d_ws;
  int* cnt = (int*)(ws + OFF_CNT);
  float* Wg = (float*)(ws + OFF_WG);
  float* bg = (float*)(ws + OFF_BG);
  unsigned short* W1F = (unsigned short*)(ws + OFF_W1F);
  unsigned short* W2F = (unsigned short*)(ws + OFF_W2F);
  uint4* lst = (uint4*)(ws + OFF_L);
  float* aux = out + (size_t)NTOK * DOUT;     // scalar output
  float* pout = aux + 1;                      // p_open [N,8]

  int maxb = 0;
  hipOccupancyMaxActiveBlocksPerMultiprocessor(&maxb, (const void*)k_fused, 256, 0);
  if (maxb < 1) maxb = 1;
  long long grid = (long long)maxb * 256;
  if (grid > 1024) grid = 1024;

  void* args[] = {(void*)&x, (void*)&Wp, (void*)&bp, (void*)&Ee,
                  (void*)&W1, (void*)&b1, (void*)&W2, (void*)&b2,
                  (void*)&W1F, (void*)&W2F, (void*)&Wg, (void*)&bg,
                  (void*)&cnt, (void*)&lst, (void*)&pout, (void*)&aux, (void*)&out};
  hipLaunchCooperativeKernel((const void*)k_fused, dim3((unsigned)grid), dim3(256),
                             args, 0, stream);
}

// Round 7
// 170.487 us; speedup vs baseline: 1.4884x; 1.4884x over previous
//
#include <hip/hip_runtime.h>

#define NTOK 65536
#define DIN 128
#define DH 256
#define DOUT 128
#define NEXP 8
#define NPAIR 28
#define CAP 12288
#define TBL 2112      // >= 65536/32 + 28
#define TAUF 5.0f
#define CSTRIDE 32    // cnt padded: one counter per 128 B

typedef __attribute__((ext_vector_type(8))) short short8;
typedef __attribute__((ext_vector_type(4))) float f32x4;

// ---- workspace layout (bytes) ----
#define OFF_CNT  0                              // 28 ints @ stride 32 ints
#define OFF_WG   4096                           // 1024 f32
#define OFF_BG   8192                           // 8 f32
#define OFF_W1F  8448                           // 8*128*256 bf16 = 524288
#define OFF_W2F  (OFF_W1F + NEXP*DIN*DH*2)      // 524288
#define OFF_L    (OFF_W2F + NEXP*DH*DOUT*2)     // 28*12288*16 = 5505024
// total ~6.6 MB

__device__ __forceinline__ unsigned short f2bf(float f) {
  union { float f; unsigned u; } v; v.f = f;
  unsigned u = v.u;
  return (unsigned short)((u + 0x7FFFu + ((u >> 16) & 1u)) >> 16);
}

// ---- kernel 1: weight conversion (blocks 0..95) + gate fuse + cnt/aux zero (block 96) ----
__global__ void k_prep(const float* __restrict__ W1, const float* __restrict__ W2,
                       unsigned short* __restrict__ W1F, unsigned short* __restrict__ W2F,
                       const float* __restrict__ Wp, const float* __restrict__ bp,
                       const float* __restrict__ Ee, float* __restrict__ Wg,
                       float* __restrict__ bg, int* __restrict__ cnt,
                       float* __restrict__ aux) {
  __shared__ float sl[32 * 257];
  int b = blockIdx.x, t = threadIdx.x;
  if (b == 96) {
    for (int i = 0; i < 4; i++) {
      int o = t + i * 256;
      int k = o >> 3, e = o & 7;
      float s = 0.f;
      for (int l = 0; l < 64; l++) s += Wp[k * 64 + l] * Ee[l * 8 + e];
      Wg[o] = s;
    }
    if (t < 8) {
      float s = 0.f;
      for (int l = 0; l < 64; l++) s += bp[l] * Ee[l * 8 + t];
      bg[t] = s;
    }
    if (t < NPAIR) cnt[t * CSTRIDE] = 0;
    if (t == 255) aux[0] = 0.f;
    return;
  }
  const float* src; unsigned short* dst;
  int stride, iters, cshift;
  if (b < 32) {
    int e = b >> 2, kk = b & 3;
    src = W1 + e * (DIN * DH) + kk * 32 * DH;
    dst = W1F + e * (DIN * DH) + kk * (32 * DH);
    stride = 257; iters = 32; cshift = 8;           // 32 x 256 slab
  } else {
    int bb = b - 32;
    int e = bb >> 3, kk = bb & 7;
    src = W2 + e * (DH * DOUT) + kk * 32 * DOUT;
    dst = W2F + e * (DH * DOUT) + kk * (32 * DOUT);
    stride = 129; iters = 16; cshift = 7;           // 32 x 128 slab
  }
  int ncols_m1 = (1 << cshift) - 1;
  for (int i = 0; i < iters; i++) {
    int idx = t + i * 256;
    int r = idx >> cshift, c = idx & ncols_m1;
    sl[r * stride + c] = src[idx];
  }
  __syncthreads();
  for (int i = 0; i < iters; i++) {
    int o = t + i * 256;                            // o = n*32 + c : B-frag linear
    int n = o >> 5, cc = o & 31;
    dst[o] = f2bf(sl[cc * stride + n]);
  }
}

// ---- kernel 2: gate, 64 tokens/block (1024 blocks; best measured shape) ----
__global__ void __launch_bounds__(256) k_gate(
    const float* __restrict__ x, const float* __restrict__ Wg, const float* __restrict__ bg,
    float* __restrict__ pout, int* __restrict__ cnt, uint4* __restrict__ lst) {
  __shared__ float xl[64 * 132];
  __shared__ float pr[256 * 9];
  __shared__ float wgl[1024];
  __shared__ float bgl[8];
  __shared__ int lc[NPAIR], lb[NPAIR];
  int t = threadIdx.x, b = blockIdx.x;
  int tok0 = b * 64;
  for (int i = 0; i < 4; i++) wgl[t + i * 256] = Wg[t + i * 256];
  if (t < 8) bgl[t] = bg[t];
  if (t < NPAIR) lc[t] = 0;
  const float4* x4 = (const float4*)(x + (size_t)tok0 * DIN);
  for (int i = 0; i < 8; i++) {
    int idx = t + i * 256;
    int r = idx >> 5, c4 = idx & 31;
    *(float4*)&xl[r * 132 + c4 * 4] = x4[r * 32 + c4];
  }
  __syncthreads();
  {
    int tok = t & 63, seg = t >> 6;
    float a0=0,a1=0,a2=0,a3=0,a4=0,a5=0,a6=0,a7=0;
    int k0 = seg * 32;
    for (int k = k0; k < k0 + 32; k++) {
      float xv = xl[tok * 132 + k];
      float4 wa = *(const float4*)&wgl[k * 8];
      float4 wb = *(const float4*)&wgl[k * 8 + 4];
      a0 += xv * wa.x; a1 += xv * wa.y; a2 += xv * wa.z; a3 += xv * wa.w;
      a4 += xv * wb.x; a5 += xv * wb.y; a6 += xv * wb.z; a7 += xv * wb.w;
    }
    float* p = &pr[t * 9];
    p[0]=a0; p[1]=a1; p[2]=a2; p[3]=a3; p[4]=a4; p[5]=a5; p[6]=a6; p[7]=a7;
  }
  __syncthreads();
  int pid = 0; unsigned pos = 0; unsigned wAb = 0, wBb = 0;
  if (t < 64) {
    float p[8];
    #pragma unroll
    for (int e = 0; e < 8; e++) {
      float lg = pr[t*9+e] + pr[(64+t)*9+e] + pr[(128+t)*9+e] + pr[(192+t)*9+e] + bgl[e];
      p[e] = 1.f / (1.f + expf(-lg / TAUF));
    }
    float* prow = pout + (size_t)(tok0 + t) * 8;
    #pragma unroll
    for (int e = 0; e < 8; e++) prow[e] = p[e];
    int i0 = 0; float v0 = -1.f;
    #pragma unroll
    for (int e = 0; e < 8; e++) if (p[e] > v0) { v0 = p[e]; i0 = e; }
    int i1 = -1; float v1 = -1.f;
    #pragma unroll
    for (int e = 0; e < 8; e++) if (e != i0 && p[e] > v1) { v1 = p[e]; i1 = e; }
    float s = v0 + v1 + 1e-10f;
    float w0 = v0 / s, w1 = v1 / s;
    int eA, eB; float wA, wB;
    if (i0 < i1) { eA = i0; eB = i1; wA = w0; wB = w1; }
    else         { eA = i1; eB = i0; wA = w1; wB = w0; }
    pid = 7 * eA - (eA * (eA - 1)) / 2 + (eB - eA - 1);   // 28 unordered pairs
    union { float f; unsigned u; } ua, ub; ua.f = wA; ub.f = wB;
    wAb = ua.u; wBb = ub.u;
    pos = (unsigned)atomicAdd(&lc[pid], 1);   // LDS atomic
  }
  __syncthreads();
  if (t < NPAIR) lb[t] = atomicAdd(&cnt[t * CSTRIDE], lc[t]);
  __syncthreads();
  if (t < 64) {
    int gi = lb[pid] + (int)pos;
    if (gi < CAP) lst[pid * CAP + gi] = make_uint4((unsigned)(tok0 + t), wAb, wBb, 0u);
  }
}

// ---- kernel 3: paired expert compute; 128-thread blocks, 32-token tiles ----
// 2-wave barrier domain, ~26 KB LDS -> 6 blocks/CU co-resident.
__global__ void __launch_bounds__(128, 3) k_expert(
    const float* __restrict__ x,
    const unsigned short* __restrict__ W1F, const unsigned short* __restrict__ W2F,
    const float* __restrict__ b1, const float* __restrict__ b2,
    const int* __restrict__ cnt, const uint4* __restrict__ lst,
    float* __restrict__ out) {
  __shared__ int cs[NPAIR];
  __shared__ int toks[32];
  __shared__ float wAs[32], wBs[32];
  __shared__ unsigned short xs[32 * 136];   // 8704 B
  __shared__ unsigned short hs[32 * 264];   // 16896 B  (total ~26.1 KB)
  int t = threadIdx.x;
  if (t < NPAIR) cs[t] = cnt[t * CSTRIDE];
  __syncthreads();
  // map flat block id -> (pair bucket, 32-token tile)
  int gid = blockIdx.x;
  int bsel = -1, tIn = 0, cum = 0;
  #pragma unroll
  for (int bb = 0; bb < NPAIR; bb++) {
    int c = cs[bb]; c = (c > CAP) ? CAP : c;
    int tb = (c + 31) >> 5;
    if (bsel < 0 && gid < cum + tb) { bsel = bb; tIn = gid - cum; }
    cum += tb;
  }
  if (bsel < 0) return;
  int eA = 0, eB = 1;
  { int r = bsel;
    #pragma unroll
    for (int a = 0; a < 7; a++) { int span = 7 - a; if (r < span) { eA = a; eB = a + 1 + r; break; } r -= span; } }
  int cntb = cs[bsel]; cntb = (cntb > CAP) ? CAP : cntb;
  int start = tIn * 32;
  int cvalid = min(32, cntb - start);
  if (t < 32) {
    if (t < cvalid) {
      uint4 en = lst[bsel * CAP + start + t];
      toks[t] = (int)en.x;
      union { unsigned u; float f; } ua, ub; ua.u = en.y; ub.u = en.z;
      wAs[t] = ua.f; wBs[t] = ub.f;
    } else { toks[t] = 0; wAs[t] = 0.f; wBs[t] = 0.f; }
  }
  __syncthreads();
  for (int i = 0; i < 8; i++) {          // gather x rows -> bf16 LDS (32 lanes per 512B row)
    int idx = i * 128 + t;
    int r = idx >> 5, c4 = idx & 31;
    float4 f = *(const float4*)(x + (size_t)toks[r] * DIN + c4 * 4);
    unsigned u0 = (unsigned)f2bf(f.x) | ((unsigned)f2bf(f.y) << 16);
    unsigned u1 = (unsigned)f2bf(f.z) | ((unsigned)f2bf(f.w) << 16);
    *(uint2*)(xs + r * 136 + c4 * 4) = make_uint2(u0, u1);
  }
  __syncthreads();
  int lane = t & 63, w = t >> 6;        // w in {0,1}
  int q = lane >> 4, n16 = lane & 15;
  const f32x4 vz = {0.f, 0.f, 0.f, 0.f};
  int cb = w * 64;                       // GEMM2 col half
  f32x4 accO[2][4];
  for (int pass = 0; pass < 2; pass++) {
    int e = pass ? eB : eA;
    if (pass) __syncthreads();   // both waves done reading hs from pass 0
    // ---- GEMM1: H = relu(X @ W1[e] + b1[e]); wave w -> hidden cols [w*128, +128) ----
    {
      const unsigned short* Bp = W1F + e * (DIN * DH) + (w * 128 + n16) * 32 + q * 8;
      float b1v[8];
      #pragma unroll
      for (int nt = 0; nt < 8; nt++) b1v[nt] = b1[e * DH + w * 128 + nt * 16 + n16];
      f32x4 acc[2][8];
      #pragma unroll
      for (int mt = 0; mt < 2; mt++)
        #pragma unroll
        for (int nt = 0; nt < 8; nt++) acc[mt][nt] = vz;
      short8 bcur[8], bnxt[8];
      #pragma unroll
      for (int nt = 0; nt < 8; nt++) bcur[nt] = *(const short8*)(Bp + nt * 512);
      #pragma unroll
      for (int kk = 0; kk < 4; kk++) {
        if (kk < 3) {
          #pragma unroll
          for (int nt = 0; nt < 8; nt++) bnxt[nt] = *(const short8*)(Bp + (kk + 1) * 8192 + nt * 512);
        }
        short8 a[2];
        #pragma unroll
        for (int mt = 0; mt < 2; mt++)
          a[mt] = *(const short8*)(xs + (mt * 16 + n16) * 136 + kk * 32 + q * 8);
        #pragma unroll
        for (int nt = 0; nt < 8; nt++)
          #pragma unroll
          for (int mt = 0; mt < 2; mt++)
            acc[mt][nt] = __builtin_amdgcn_mfma_f32_16x16x32_bf16(a[mt], bcur[nt], acc[mt][nt], 0, 0, 0);
        #pragma unroll
        for (int nt = 0; nt < 8; nt++) bcur[nt] = bnxt[nt];
      }
      #pragma unroll
      for (int mt = 0; mt < 2; mt++)
        #pragma unroll
        for (int nt = 0; nt < 8; nt++)
          #pragma unroll
          for (int r = 0; r < 4; r++) {
            float v = fmaxf(acc[mt][nt][r] + b1v[nt], 0.f);
            hs[(mt * 16 + q * 4 + r) * 264 + w * 128 + nt * 16 + n16] = f2bf(v);
          }
    }
    __syncthreads();
    // ---- GEMM2: acc2 = H @ W2[e]; wave w -> rows 0..31, cols [w*64, +64) ----
    {
      const unsigned short* Bp = W2F + e * (DH * DOUT) + (cb + n16) * 32 + q * 8;
      float b2v[4];
      #pragma unroll
      for (int nt = 0; nt < 4; nt++) b2v[nt] = b2[e * DOUT + cb + nt * 16 + n16];
      f32x4 acc2[2][4];
      #pragma unroll
      for (int m = 0; m < 2; m++)
        #pragma unroll
        for (int nt = 0; nt < 4; nt++) acc2[m][nt] = vz;
      short8 bcur[8], bnxt[8];
      #pragma unroll
      for (int i = 0; i < 8; i++)
        bcur[i] = *(const short8*)(Bp + (i >> 2) * 4096 + (i & 3) * 512);
      #pragma unroll
      for (int kc = 0; kc < 4; kc++) {
        if (kc < 3) {
          #pragma unroll
          for (int i = 0; i < 8; i++)
            bnxt[i] = *(const short8*)(Bp + (kc * 2 + 2 + (i >> 2)) * 4096 + (i & 3) * 512);
        }
        #pragma unroll
        for (int kk2 = 0; kk2 < 2; kk2++) {
          int kk = kc * 2 + kk2;
          short8 a[2];
          #pragma unroll
          for (int m = 0; m < 2; m++)
            a[m] = *(const short8*)(hs + (m * 16 + n16) * 264 + kk * 32 + q * 8);
          #pragma unroll
          for (int nt = 0; nt < 4; nt++)
            #pragma unroll
            for (int m = 0; m < 2; m++)
              acc2[m][nt] = __builtin_amdgcn_mfma_f32_16x16x32_bf16(a[m], bcur[kk2 * 4 + nt], acc2[m][nt], 0, 0, 0);
        }
        #pragma unroll
        for (int i = 0; i < 8; i++) bcur[i] = bnxt[i];
      }
      const float* wsel = pass ? wBs : wAs;
      #pragma unroll
      for (int m = 0; m < 2; m++)
        #pragma unroll
        for (int r = 0; r < 4; r++) {
          float wv = wsel[m * 16 + q * 4 + r];
          #pragma unroll
          for (int nt = 0; nt < 4; nt++) {
            float v = (acc2[m][nt][r] + b2v[nt]) * wv;
            if (pass) accO[m][nt][r] += v;
            else      accO[m][nt][r] = v;
          }
        }
    }
  }
  // single store per output element
  #pragma unroll
  for (int m = 0; m < 2; m++)
    #pragma unroll
    for (int r = 0; r < 4; r++) {
      int row = m * 16 + q * 4 + r;
      if (row < cvalid) {
        float* orow = out + (size_t)toks[row] * DOUT + cb + n16;
        #pragma unroll
        for (int nt = 0; nt < 4; nt++) orow[nt * 16] = accO[m][nt][r];
      }
    }
}

extern "C" void kernel_launch(void* const* d_in, const int* in_sizes, int n_in,
                              void* d_out, int out_size, void* d_ws, size_t ws_size,
                              hipStream_t stream) {
  const float* x  = (const float*)d_in[0];
  const float* Wp = (const float*)d_in[1];
  const float* bp = (const float*)d_in[2];
  const float* Ee = (const float*)d_in[3];
  const float* W1 = (const float*)d_in[4];
  const float* b1 = (const float*)d_in[5];
  const float* W2 = (const float*)d_in[6];
  const float* b2 = (const float*)d_in[7];
  float* out = (float*)d_out;
  char* ws = (char*)d_ws;
  int* cnt = (int*)(ws + OFF_CNT);
  float* Wg = (float*)(ws + OFF_WG);
  float* bg = (float*)(ws + OFF_BG);
  unsigned short* W1F = (unsigned short*)(ws + OFF_W1F);
  unsigned short* W2F = (unsigned short*)(ws + OFF_W2F);
  uint4* lst = (uint4*)(ws + OFF_L);
  float* aux = out + (size_t)NTOK * DOUT;     // scalar output
  float* pout = aux + 1;                      // p_open [N,8]

  k_prep<<<97, 256, 0, stream>>>(W1, W2, W1F, W2F, Wp, bp, Ee, Wg, bg, cnt, aux);
  k_gate<<<NTOK / 64, 256, 0, stream>>>(x, Wg, bg, pout, cnt, lst);
  k_expert<<<TBL, 128, 0, stream>>>(x, W1F, W2F, b1, b2, cnt, lst, out);
}

// Round 8
// 161.480 us; speedup vs baseline: 1.5714x; 1.0558x over previous
//
#include <hip/hip_runtime.h>

#define NTOK 65536
#define DIN 128
#define DH 256
#define DOUT 128
#define NEXP 8
#define NPAIR 28
#define CAP 12288
#define TBL 1056
#define TAUF 5.0f
#define CSTRIDE 32    // cnt padded: one counter per 128 B

typedef __attribute__((ext_vector_type(8))) short short8;
typedef __attribute__((ext_vector_type(4))) float f32x4;

// ---- workspace layout (bytes) ----
#define OFF_CNT  0                              // 28 ints @ stride 32 ints
#define OFF_WG   4096                           // 1024 f32
#define OFF_BG   8192                           // 8 f32
#define OFF_W1F  8448                           // 8*128*256 bf16 = 524288
#define OFF_W2F  (OFF_W1F + NEXP*DIN*DH*2)      // 524288
#define OFF_L    (OFF_W2F + NEXP*DH*DOUT*2)     // 28*12288*16 = 5505024
// total ~6.6 MB

__device__ __forceinline__ unsigned short f2bf(float f) {
  union { float f; unsigned u; } v; v.f = f;
  unsigned u = v.u;
  return (unsigned short)((u + 0x7FFFu + ((u >> 16) & 1u)) >> 16);
}

// ---- kernel 1: weight conversion (blocks 0..95) + gate fuse + cnt/aux zero (block 96) ----
__global__ void k_prep(const float* __restrict__ W1, const float* __restrict__ W2,
                       unsigned short* __restrict__ W1F, unsigned short* __restrict__ W2F,
                       const float* __restrict__ Wp, const float* __restrict__ bp,
                       const float* __restrict__ Ee, float* __restrict__ Wg,
                       float* __restrict__ bg, int* __restrict__ cnt,
                       float* __restrict__ aux) {
  __shared__ float sl[32 * 257];
  int b = blockIdx.x, t = threadIdx.x;
  if (b == 96) {
    for (int i = 0; i < 4; i++) {
      int o = t + i * 256;
      int k = o >> 3, e = o & 7;
      float s = 0.f;
      for (int l = 0; l < 64; l++) s += Wp[k * 64 + l] * Ee[l * 8 + e];
      Wg[o] = s;
    }
    if (t < 8) {
      float s = 0.f;
      for (int l = 0; l < 64; l++) s += bp[l] * Ee[l * 8 + t];
      bg[t] = s;
    }
    if (t < NPAIR) cnt[t * CSTRIDE] = 0;
    if (t == 255) aux[0] = 0.f;
    return;
  }
  const float* src; unsigned short* dst;
  int stride, iters, cshift;
  if (b < 32) {
    int e = b >> 2, kk = b & 3;
    src = W1 + e * (DIN * DH) + kk * 32 * DH;
    dst = W1F + e * (DIN * DH) + kk * (32 * DH);
    stride = 257; iters = 32; cshift = 8;           // 32 x 256 slab
  } else {
    int bb = b - 32;
    int e = bb >> 3, kk = bb & 7;
    src = W2 + e * (DH * DOUT) + kk * 32 * DOUT;
    dst = W2F + e * (DH * DOUT) + kk * (32 * DOUT);
    stride = 129; iters = 16; cshift = 7;           // 32 x 128 slab
  }
  int ncols_m1 = (1 << cshift) - 1;
  for (int i = 0; i < iters; i++) {
    int idx = t + i * 256;
    int r = idx >> cshift, c = idx & ncols_m1;
    sl[r * stride + c] = src[idx];
  }
  __syncthreads();
  for (int i = 0; i < iters; i++) {
    int o = t + i * 256;                            // o = n*32 + c : B-frag linear
    int n = o >> 5, cc = o & 31;
    dst[o] = f2bf(sl[cc * stride + n]);
  }
}

// ---- kernel 2: gate, 64 tokens/block (1024 blocks; best measured shape) ----
__global__ void __launch_bounds__(256) k_gate(
    const float* __restrict__ x, const float* __restrict__ Wg, const float* __restrict__ bg,
    float* __restrict__ pout, int* __restrict__ cnt, uint4* __restrict__ lst) {
  __shared__ float xl[64 * 132];
  __shared__ float pr[256 * 9];
  __shared__ float wgl[1024];
  __shared__ float bgl[8];
  __shared__ int lc[NPAIR], lb[NPAIR];
  int t = threadIdx.x, b = blockIdx.x;
  int tok0 = b * 64;
  for (int i = 0; i < 4; i++) wgl[t + i * 256] = Wg[t + i * 256];
  if (t < 8) bgl[t] = bg[t];
  if (t < NPAIR) lc[t] = 0;
  const float4* x4 = (const float4*)(x + (size_t)tok0 * DIN);
  for (int i = 0; i < 8; i++) {
    int idx = t + i * 256;
    int r = idx >> 5, c4 = idx & 31;
    *(float4*)&xl[r * 132 + c4 * 4] = x4[r * 32 + c4];
  }
  __syncthreads();
  {
    int tok = t & 63, seg = t >> 6;
    float a0=0,a1=0,a2=0,a3=0,a4=0,a5=0,a6=0,a7=0;
    int k0 = seg * 32;
    for (int k = k0; k < k0 + 32; k++) {
      float xv = xl[tok * 132 + k];
      float4 wa = *(const float4*)&wgl[k * 8];
      float4 wb = *(const float4*)&wgl[k * 8 + 4];
      a0 += xv * wa.x; a1 += xv * wa.y; a2 += xv * wa.z; a3 += xv * wa.w;
      a4 += xv * wb.x; a5 += xv * wb.y; a6 += xv * wb.z; a7 += xv * wb.w;
    }
    float* p = &pr[t * 9];
    p[0]=a0; p[1]=a1; p[2]=a2; p[3]=a3; p[4]=a4; p[5]=a5; p[6]=a6; p[7]=a7;
  }
  __syncthreads();
  int pid = 0; unsigned pos = 0; unsigned wAb = 0, wBb = 0;
  if (t < 64) {
    float p[8];
    #pragma unroll
    for (int e = 0; e < 8; e++) {
      float lg = pr[t*9+e] + pr[(64+t)*9+e] + pr[(128+t)*9+e] + pr[(192+t)*9+e] + bgl[e];
      p[e] = 1.f / (1.f + expf(-lg / TAUF));
    }
    float* prow = pout + (size_t)(tok0 + t) * 8;
    #pragma unroll
    for (int e = 0; e < 8; e++) prow[e] = p[e];
    int i0 = 0; float v0 = -1.f;
    #pragma unroll
    for (int e = 0; e < 8; e++) if (p[e] > v0) { v0 = p[e]; i0 = e; }
    int i1 = -1; float v1 = -1.f;
    #pragma unroll
    for (int e = 0; e < 8; e++) if (e != i0 && p[e] > v1) { v1 = p[e]; i1 = e; }
    float s = v0 + v1 + 1e-10f;
    float w0 = v0 / s, w1 = v1 / s;
    int eA, eB; float wA, wB;
    if (i0 < i1) { eA = i0; eB = i1; wA = w0; wB = w1; }
    else         { eA = i1; eB = i0; wA = w1; wB = w0; }
    pid = 7 * eA - (eA * (eA - 1)) / 2 + (eB - eA - 1);   // 28 unordered pairs
    union { float f; unsigned u; } ua, ub; ua.f = wA; ub.f = wB;
    wAb = ua.u; wBb = ub.u;
    pos = (unsigned)atomicAdd(&lc[pid], 1);   // LDS atomic
  }
  __syncthreads();
  if (t < NPAIR) lb[t] = atomicAdd(&cnt[t * CSTRIDE], lc[t]);
  __syncthreads();
  if (t < 64) {
    int gi = lb[pid] + (int)pos;
    if (gi < CAP) lst[pid * CAP + gi] = make_uint4((unsigned)(tok0 + t), wAb, wBb, 0u);
  }
}

// ---- kernel 3: paired expert compute; upfront 16-load B panels (deep MLP),
// GEMM2 de-duplicated (each wave: 32 cols x all 64 rows) ----
__global__ void __launch_bounds__(256, 2) k_expert(
    const float* __restrict__ x,
    const unsigned short* __restrict__ W1F, const unsigned short* __restrict__ W2F,
    const float* __restrict__ b1, const float* __restrict__ b2,
    const int* __restrict__ cnt, const uint4* __restrict__ lst,
    float* __restrict__ out) {
  __shared__ int cs[NPAIR];
  __shared__ int toks[64];
  __shared__ float wAs[64], wBs[64];
  __shared__ unsigned short xs[64 * 136];   // 17408 B
  __shared__ unsigned short hs[64 * 264];   // 33792 B
  int t = threadIdx.x;
  if (t < NPAIR) cs[t] = cnt[t * CSTRIDE];
  __syncthreads();
  int gid = blockIdx.x;
  int bsel = -1, tIn = 0, cum = 0;
  #pragma unroll
  for (int bb = 0; bb < NPAIR; bb++) {
    int c = cs[bb]; c = (c > CAP) ? CAP : c;
    int tb = (c + 63) >> 6;
    if (bsel < 0 && gid < cum + tb) { bsel = bb; tIn = gid - cum; }
    cum += tb;
  }
  if (bsel < 0) return;
  int eA = 0, eB = 1;
  { int r = bsel;
    #pragma unroll
    for (int a = 0; a < 7; a++) { int span = 7 - a; if (r < span) { eA = a; eB = a + 1 + r; break; } r -= span; } }
  int cntb = cs[bsel]; cntb = (cntb > CAP) ? CAP : cntb;
  int start = tIn * 64;
  int cvalid = min(64, cntb - start);
  if (t < 64) {
    if (t < cvalid) {
      uint4 en = lst[bsel * CAP + start + t];
      toks[t] = (int)en.x;
      union { unsigned u; float f; } ua, ub; ua.u = en.y; ub.u = en.z;
      wAs[t] = ua.f; wBs[t] = ub.f;
    } else { toks[t] = 0; wAs[t] = 0.f; wBs[t] = 0.f; }
  }
  __syncthreads();
  for (int i = 0; i < 8; i++) {          // gather x rows -> bf16 LDS
    int idx = i * 256 + t;
    int r = idx >> 5, c4 = idx & 31;
    float4 f = *(const float4*)(x + (size_t)toks[r] * DIN + c4 * 4);
    unsigned u0 = (unsigned)f2bf(f.x) | ((unsigned)f2bf(f.y) << 16);
    unsigned u1 = (unsigned)f2bf(f.z) | ((unsigned)f2bf(f.w) << 16);
    *(uint2*)(xs + r * 136 + c4 * 4) = make_uint2(u0, u1);
  }
  __syncthreads();
  int lane = t & 63, w = t >> 6;
  int q = lane >> 4, n16 = lane & 15;
  const f32x4 vz = {0.f, 0.f, 0.f, 0.f};
  int cb = w * 32;                      // GEMM2: wave w owns cols [32w, 32w+32)
  f32x4 accO[4][2];
  #pragma unroll
  for (int pass = 0; pass < 2; pass++) {
    int e = pass ? eB : eA;
    if (pass) __syncthreads();   // all waves done reading hs from pass 0
    // ---- GEMM1: H = relu(X @ W1[e] + b1[e]); wave w -> hidden cols [w*64, +64) ----
    {
      const unsigned short* Bp = W1F + e * (DIN * DH) + (w * 64 + n16) * 32 + q * 8;
      short8 bf[16];                    // entire 64x128 B-panel: 16 loads in flight
      #pragma unroll
      for (int kk = 0; kk < 4; kk++)
        #pragma unroll
        for (int nt = 0; nt < 4; nt++)
          bf[kk * 4 + nt] = *(const short8*)(Bp + kk * 8192 + nt * 512);
      float b1v[4];
      #pragma unroll
      for (int nt = 0; nt < 4; nt++) b1v[nt] = b1[e * DH + w * 64 + nt * 16 + n16];
      f32x4 acc[4][4];
      #pragma unroll
      for (int mt = 0; mt < 4; mt++)
        #pragma unroll
        for (int nt = 0; nt < 4; nt++) acc[mt][nt] = vz;
      #pragma unroll
      for (int kk = 0; kk < 4; kk++) {
        short8 a[4];
        #pragma unroll
        for (int mt = 0; mt < 4; mt++)
          a[mt] = *(const short8*)(xs + (mt * 16 + n16) * 136 + kk * 32 + q * 8);
        #pragma unroll
        for (int nt = 0; nt < 4; nt++)
          #pragma unroll
          for (int mt = 0; mt < 4; mt++)
            acc[mt][nt] = __builtin_amdgcn_mfma_f32_16x16x32_bf16(a[mt], bf[kk * 4 + nt], acc[mt][nt], 0, 0, 0);
      }
      #pragma unroll
      for (int mt = 0; mt < 4; mt++)
        #pragma unroll
        for (int nt = 0; nt < 4; nt++)
          #pragma unroll
          for (int r = 0; r < 4; r++) {
            float v = fmaxf(acc[mt][nt][r] + b1v[nt], 0.f);
            hs[(mt * 16 + q * 4 + r) * 264 + w * 64 + nt * 16 + n16] = f2bf(v);
          }
    }
    // prefetch GEMM2 B-panel (independent of hs) -- completes across the barrier
    short8 bf2[16];                     // 32 cols x 256 k: 16 loads in flight
    {
      const unsigned short* Bp2 = W2F + e * (DH * DOUT) + (cb + n16) * 32 + q * 8;
      #pragma unroll
      for (int kk = 0; kk < 8; kk++)
        #pragma unroll
        for (int nt = 0; nt < 2; nt++)
          bf2[kk * 2 + nt] = *(const short8*)(Bp2 + kk * 4096 + nt * 512);
    }
    __syncthreads();
    // ---- GEMM2: acc2 = H @ W2[e]; wave w -> all 64 rows, cols [w*32, +32) ----
    {
      float b2v[2];
      #pragma unroll
      for (int nt = 0; nt < 2; nt++) b2v[nt] = b2[e * DOUT + cb + nt * 16 + n16];
      f32x4 acc2[4][2];
      #pragma unroll
      for (int m = 0; m < 4; m++)
        #pragma unroll
        for (int nt = 0; nt < 2; nt++) acc2[m][nt] = vz;
      #pragma unroll
      for (int kk = 0; kk < 8; kk++) {
        short8 a[4];
        #pragma unroll
        for (int m = 0; m < 4; m++)
          a[m] = *(const short8*)(hs + (m * 16 + n16) * 264 + kk * 32 + q * 8);
        #pragma unroll
        for (int nt = 0; nt < 2; nt++)
          #pragma unroll
          for (int m = 0; m < 4; m++)
            acc2[m][nt] = __builtin_amdgcn_mfma_f32_16x16x32_bf16(a[m], bf2[kk * 2 + nt], acc2[m][nt], 0, 0, 0);
      }
      const float* wsel = pass ? wBs : wAs;
      #pragma unroll
      for (int m = 0; m < 4; m++)
        #pragma unroll
        for (int r = 0; r < 4; r++) {
          float wv = wsel[m * 16 + q * 4 + r];
          #pragma unroll
          for (int nt = 0; nt < 2; nt++) {
            float v = (acc2[m][nt][r] + b2v[nt]) * wv;
            if (pass) accO[m][nt][r] += v;
            else      accO[m][nt][r] = v;
          }
        }
    }
  }
  // single store per output element (wave w -> cols [32w,+32), rows all)
  #pragma unroll
  for (int m = 0; m < 4; m++)
    #pragma unroll
    for (int r = 0; r < 4; r++) {
      int row = m * 16 + q * 4 + r;
      if (row < cvalid) {
        float* orow = out + (size_t)toks[row] * DOUT + cb + n16;
        orow[0]  = accO[m][0][r];
        orow[16] = accO[m][1][r];
      }
    }
}

extern "C" void kernel_launch(void* const* d_in, const int* in_sizes, int n_in,
                              void* d_out, int out_size, void* d_ws, size_t ws_size,
                              hipStream_t stream) {
  const float* x  = (const float*)d_in[0];
  const float* Wp = (const float*)d_in[1];
  const float* bp = (const float*)d_in[2];
  const float* Ee = (const float*)d_in[3];
  const float* W1 = (const float*)d_in[4];
  const float* b1 = (const float*)d_in[5];
  const float* W2 = (const float*)d_in[6];
  const float* b2 = (const float*)d_in[7];
  float* out = (float*)d_out;
  char* ws = (char*)d_ws;
  int* cnt = (int*)(ws + OFF_CNT);
  float* Wg = (float*)(ws + OFF_WG);
  float* bg = (float*)(ws + OFF_BG);
  unsigned short* W1F = (unsigned short*)(ws + OFF_W1F);
  unsigned short* W2F = (unsigned short*)(ws + OFF_W2F);
  uint4* lst = (uint4*)(ws + OFF_L);
  float* aux = out + (size_t)NTOK * DOUT;     // scalar output
  float* pout = aux + 1;                      // p_open [N,8]

  k_prep<<<97, 256, 0, stream>>>(W1, W2, W1F, W2F, Wp, bp, Ee, Wg, bg, cnt, aux);
  k_gate<<<NTOK / 64, 256, 0, stream>>>(x, Wg, bg, pout, cnt, lst);
  k_expert<<<TBL, 256, 0, stream>>>(x, W1F, W2F, b1, b2, cnt, lst, out);
}